// Round 1
// baseline (196.719 us; speedup 1.0000x reference)
//
#include <hip/hip_runtime.h>
#include <stddef.h>

// Problem constants (fixed by setup_inputs)
constexpr int B = 32;
constexpr int T = 2048;
constexpr int F = 512;
constexpr int U = 128;
constexpr float NEG_BIG = -1.0e9f;

constexpr int TM = 64;   // frames per block (pass 1)
constexpr int TK = 32;   // K chunk

// ---------------------------------------------------------------------------
// Pass 1: scores[m] = relu(x[m,:] @ W1 + b1) @ W2 + b2, masked to NEG_BIG
//         when the frame is all-zero. Tiled fp32 GEMM, M=B*T, K=F, N=U with
//         fused ReLU + W2 reduction epilogue.
// ---------------------------------------------------------------------------
__global__ __launch_bounds__(256) void score_kernel(
    const float* __restrict__ x,    // [B*T, F]
    const float* __restrict__ W1,   // [F, U]
    const float* __restrict__ b1,   // [U]
    const float* __restrict__ W2,   // [U] (U,1 flattened)
    const float* __restrict__ b2,   // [1]
    float* __restrict__ scores)     // [B*T]
{
    __shared__ float xs[TM][TK + 1];          // +1 pad: conflict-free column reads
    __shared__ float ws[TK][U];
    __shared__ unsigned nz[TM];
    __shared__ float partial[TM][16];
    __shared__ float sb1[U];
    __shared__ float sW2[U];

    const int tid = threadIdx.x;
    const int m0  = blockIdx.x * TM;

    if (tid < U) { sb1[tid] = b1[tid]; sW2[tid] = W2[tid]; }
    if (tid < TM) nz[tid] = 0u;
    __syncthreads();

    // thread (ty,tx): ty in [0,16) -> 4 frames, tx in [0,16) -> 8 u's
    const int ty = tid >> 4;
    const int tx = tid & 15;

    float acc[4][8];
#pragma unroll
    for (int i = 0; i < 4; ++i)
#pragma unroll
        for (int j = 0; j < 8; ++j) acc[i][j] = 0.0f;

    for (int k0 = 0; k0 < F; k0 += TK) {
        // stage x tile: 64 frames x 32 k = 512 float4 -> 2 per thread
#pragma unroll
        for (int r = 0; r < 2; ++r) {
            int q  = tid + r * 256;
            int fr = q >> 3;            // frame within tile
            int kk = (q & 7) * 4;       // k offset within chunk
            const float4 v = *reinterpret_cast<const float4*>(
                &x[(size_t)(m0 + fr) * F + k0 + kk]);
            xs[fr][kk + 0] = v.x; xs[fr][kk + 1] = v.y;
            xs[fr][kk + 2] = v.z; xs[fr][kk + 3] = v.w;
            if (v.x != 0.0f || v.y != 0.0f || v.z != 0.0f || v.w != 0.0f)
                nz[fr] = 1u;            // benign write-write race (all write 1)
        }
        // stage W1 chunk: 32 rows x 128 u = 1024 float4 -> 4 per thread
#pragma unroll
        for (int r = 0; r < 4; ++r) {
            int q  = tid + r * 256;
            int kr = q >> 5;            // row within chunk (32 float4 per row)
            int uq = (q & 31) * 4;
            *reinterpret_cast<float4*>(&ws[kr][uq]) =
                *reinterpret_cast<const float4*>(&W1[(size_t)(k0 + kr) * U + uq]);
        }
        __syncthreads();

#pragma unroll
        for (int kk = 0; kk < TK; ++kk) {
            float xv[4];
#pragma unroll
            for (int i = 0; i < 4; ++i) xv[i] = xs[ty * 4 + i][kk];
            const float4 w0 = *reinterpret_cast<const float4*>(&ws[kk][tx * 8]);
            const float4 w1 = *reinterpret_cast<const float4*>(&ws[kk][tx * 8 + 4]);
            const float wv[8] = { w0.x, w0.y, w0.z, w0.w, w1.x, w1.y, w1.z, w1.w };
#pragma unroll
            for (int i = 0; i < 4; ++i)
#pragma unroll
                for (int j = 0; j < 8; ++j) acc[i][j] += xv[i] * wv[j];
        }
        __syncthreads();
    }

    // epilogue: relu + b1, dot with W2 over this thread's 8 u's
#pragma unroll
    for (int i = 0; i < 4; ++i) {
        float s = 0.0f;
#pragma unroll
        for (int j = 0; j < 8; ++j) {
            const int u = tx * 8 + j;
            float h = acc[i][j] + sb1[u];
            h = h > 0.0f ? h : 0.0f;
            s += h * sW2[u];
        }
        partial[ty * 4 + i][tx] = s;
    }
    __syncthreads();

    if (tid < TM) {
        float s = 0.0f;
#pragma unroll
        for (int j = 0; j < 16; ++j) s += partial[tid][j];
        s += b2[0];
        scores[m0 + tid] = nz[tid] ? s : NEG_BIG;
    }
}

// ---------------------------------------------------------------------------
// Pass 2: per batch row, sel[t] = 1 iff frame t is in the top-k.
// rank(t) = #{t' : s' > s} + #{t' : s' == s && t' < t}; selected iff rank < k.
// This exactly reproduces lax.top_k's stable (lower-index-first) tie handling.
// ---------------------------------------------------------------------------
__global__ __launch_bounds__(256) void topk_kernel(
    const float* __restrict__ scores,  // [B*T]
    const int* __restrict__ kp,        // [1]
    int* __restrict__ sel)             // [B*T]
{
    __shared__ float srow[T];

    const int b     = blockIdx.x >> 3;   // 8 chunks of 256 frames per row
    const int chunk = blockIdx.x & 7;
    const float* row = scores + (size_t)b * T;

    for (int i = threadIdx.x; i < T / 4; i += 256)
        reinterpret_cast<float4*>(srow)[i] =
            reinterpret_cast<const float4*>(row)[i];
    __syncthreads();

    const int t  = chunk * 256 + threadIdx.x;
    const float s = srow[t];
    int cnt = 0;
    for (int i = 0; i < T / 4; ++i) {
        const float4 v = reinterpret_cast<const float4*>(srow)[i];
        const int base = i * 4;
        cnt += (v.x > s) || (v.x == s && (base + 0) < t);
        cnt += (v.y > s) || (v.y == s && (base + 1) < t);
        cnt += (v.z > s) || (v.z == s && (base + 2) < t);
        cnt += (v.w > s) || (v.w == s && (base + 3) < t);
    }
    const int k = kp[0];
    sel[(size_t)b * T + t] = (cnt < k) ? 1 : 0;
}

// ---------------------------------------------------------------------------
// Pass 3: out[m, :] = sel[m] ? x[m, :] : 0. Reads x only for selected frames.
// ---------------------------------------------------------------------------
__global__ __launch_bounds__(256) void out_kernel(
    const float* __restrict__ x,
    const int* __restrict__ sel,
    float* __restrict__ out)
{
    const size_t total  = (size_t)B * T * (F / 4);   // float4 count
    const size_t stride = (size_t)gridDim.x * blockDim.x;
    for (size_t idx = (size_t)blockIdx.x * blockDim.x + threadIdx.x;
         idx < total; idx += stride) {
        const size_t frame = idx >> 7;               // F/4 = 128 float4 per frame
        float4 v = make_float4(0.0f, 0.0f, 0.0f, 0.0f);
        if (sel[frame])
            v = reinterpret_cast<const float4*>(x)[idx];
        reinterpret_cast<float4*>(out)[idx] = v;
    }
}

// ---------------------------------------------------------------------------
extern "C" void kernel_launch(void* const* d_in, const int* in_sizes, int n_in,
                              void* d_out, int out_size, void* d_ws, size_t ws_size,
                              hipStream_t stream)
{
    const float* x  = (const float*)d_in[0];
    const float* W1 = (const float*)d_in[1];
    const float* b1 = (const float*)d_in[2];
    const float* W2 = (const float*)d_in[3];
    const float* b2 = (const float*)d_in[4];
    const int*   kp = (const int*)d_in[5];

    float* scores = (float*)d_ws;                                 // 256 KB
    int*   sel    = (int*)((char*)d_ws + (size_t)B * T * sizeof(float)); // 256 KB

    float* out = (float*)d_out;

    // Pass 1: 1024 blocks x 256 threads, 64 frames each
    score_kernel<<<(B * T) / TM, 256, 0, stream>>>(x, W1, b1, W2, b2, scores);

    // Pass 2: 32 rows x 8 chunks
    topk_kernel<<<B * 8, 256, 0, stream>>>(scores, kp, sel);

    // Pass 3: grid-stride over 8.4M float4
    out_kernel<<<4096, 256, 0, stream>>>(x, sel, out);
}

// Round 2
// 128.416 us; speedup vs baseline: 1.5319x; 1.5319x over previous
//
#include <hip/hip_runtime.h>
#include <stddef.h>

// Problem constants (fixed by setup_inputs)
constexpr int B = 32;
constexpr int T = 2048;
constexpr int F = 512;   // K
constexpr int U = 128;   // N
constexpr float NEG_BIG = -1.0e9f;

typedef __attribute__((ext_vector_type(8))) short short8;      // MFMA A/B frag (8 bf16)
typedef __attribute__((ext_vector_type(4))) float f32x4;       // MFMA C/D frag
typedef __attribute__((ext_vector_type(4))) unsigned short u16x4;

__device__ __forceinline__ unsigned short f2bf(float f) {
    unsigned int u = __float_as_uint(f);
    u += 0x7FFFu + ((u >> 16) & 1u);     // round-to-nearest-even
    return (unsigned short)(u >> 16);
}
__device__ __forceinline__ float bf2f(unsigned short h) {
    return __uint_as_float(((unsigned int)h) << 16);
}

// ---------------------------------------------------------------------------
// Prep: W1 [F,U] fp32 -> transposed split-bf16 W1T_hi/lo [U,F].
// Tiny (65536 elems), runs once per launch.
// ---------------------------------------------------------------------------
__global__ __launch_bounds__(256) void prep_w(
    const float* __restrict__ W1,
    unsigned short* __restrict__ WThi,
    unsigned short* __restrict__ WTlo)
{
    const int idx = blockIdx.x * 256 + threadIdx.x;   // 0..65535
    const int k = idx >> 7;          // F row
    const int u = idx & 127;         // U col
    const float w = W1[idx];
    const unsigned short hi = f2bf(w);
    const unsigned short lo = f2bf(w - bf2f(hi));
    WThi[(size_t)u * F + k] = hi;
    WTlo[(size_t)u * F + k] = lo;
}

// ---------------------------------------------------------------------------
// Pass 1: scores via split-bf16 MFMA.
// Block: 256 thr = 4 waves, BM=64 frames, TK=32 per step.
// Wave w computes all 64 frames x u-cols [(2w)*16, (2w+2)*16).
// acc[mf][j] (16x16 tile): x_hi*W_hi + x_hi*W_lo + x_lo*W_hi.
// Epilogue: relu(acc + b1) . W2, 16-lane shfl reduce, cross-wave LDS reduce.
// ---------------------------------------------------------------------------
constexpr int LDK = 40;   // bf16 elems per LDS row (32 + 8 pad = 80 B stride)

__global__ __launch_bounds__(256) void score_kernel(
    const float* __restrict__ x,            // [B*T, F]
    const unsigned short* __restrict__ WThi,// [U, F] bf16 bits
    const unsigned short* __restrict__ WTlo,// [U, F]
    const float* __restrict__ b1,           // [U]
    const float* __restrict__ W2,           // [U]
    const float* __restrict__ b2,           // [1]
    float* __restrict__ scores)             // [B*T]
{
    __shared__ __align__(16) unsigned short xs_hi[64 * LDK];
    __shared__ __align__(16) unsigned short xs_lo[64 * LDK];
    __shared__ __align__(16) unsigned short wt_hi[U * LDK];
    __shared__ __align__(16) unsigned short wt_lo[U * LDK];
    __shared__ unsigned nz[64];
    __shared__ float partial[64][4];

    const int tid  = threadIdx.x;
    const int wid  = tid >> 6;
    const int lane = tid & 63;
    const int l15  = lane & 15;
    const int g    = lane >> 4;        // 16-lane group within wave
    const int m0   = blockIdx.x * 64;

    if (tid < 64) nz[tid] = 0u;

    // epilogue constants for this lane's two u-columns
    float b1v[2], w2v[2];
#pragma unroll
    for (int j = 0; j < 2; ++j) {
        const int u = (2 * wid + j) * 16 + l15;
        b1v[j] = b1[u];
        w2v[j] = W2[u];
    }

    f32x4 acc[4][2] = {};   // [m-frag][n-frag], fp32 accumulators

    __syncthreads();        // nz init visible before staging

    for (int k0 = 0; k0 < F; k0 += 32) {
        // ---- stage x tile: 64 frames x 32 k fp32 -> split bf16 ----
#pragma unroll
        for (int r = 0; r < 2; ++r) {
            const int q  = tid + r * 256;
            const int fr = q >> 3;            // frame in tile
            const int kk = (q & 7) * 4;       // k offset
            const float4 v = *reinterpret_cast<const float4*>(
                &x[(size_t)(m0 + fr) * F + k0 + kk]);
            u16x4 hv, lv;
            hv.x = f2bf(v.x); hv.y = f2bf(v.y); hv.z = f2bf(v.z); hv.w = f2bf(v.w);
            lv.x = f2bf(v.x - bf2f(hv.x));
            lv.y = f2bf(v.y - bf2f(hv.y));
            lv.z = f2bf(v.z - bf2f(hv.z));
            lv.w = f2bf(v.w - bf2f(hv.w));
            *reinterpret_cast<u16x4*>(&xs_hi[fr * LDK + kk]) = hv;
            *reinterpret_cast<u16x4*>(&xs_lo[fr * LDK + kk]) = lv;
            if (v.x != 0.0f || v.y != 0.0f || v.z != 0.0f || v.w != 0.0f)
                nz[fr] = 1u;   // benign write-write race (all write 1)
        }
        // ---- stage W1T chunk: 128 u-rows x 32 k (hi & lo) ----
        {
            const int n    = tid >> 1;
            const int half = tid & 1;
            const float4* sh = reinterpret_cast<const float4*>(
                WThi + (size_t)n * F + k0 + half * 16);
            const float4* sl = reinterpret_cast<const float4*>(
                WTlo + (size_t)n * F + k0 + half * 16);
            float4* dh = reinterpret_cast<float4*>(&wt_hi[n * LDK + half * 16]);
            float4* dl = reinterpret_cast<float4*>(&wt_lo[n * LDK + half * 16]);
            dh[0] = sh[0]; dh[1] = sh[1];
            dl[0] = sl[0]; dl[1] = sl[1];
        }
        __syncthreads();

        // ---- MFMA: 4 m-frags x 2 n-frags x 3 products ----
        short8 bh[2], bl[2];
#pragma unroll
        for (int j = 0; j < 2; ++j) {
            const int n = (2 * wid + j) * 16 + l15;
            bh[j] = *reinterpret_cast<const short8*>(&wt_hi[n * LDK + g * 8]);
            bl[j] = *reinterpret_cast<const short8*>(&wt_lo[n * LDK + g * 8]);
        }
#pragma unroll
        for (int mf = 0; mf < 4; ++mf) {
            const short8 ah = *reinterpret_cast<const short8*>(
                &xs_hi[(mf * 16 + l15) * LDK + g * 8]);
            const short8 al = *reinterpret_cast<const short8*>(
                &xs_lo[(mf * 16 + l15) * LDK + g * 8]);
#pragma unroll
            for (int j = 0; j < 2; ++j) {
                acc[mf][j] = __builtin_amdgcn_mfma_f32_16x16x32_bf16(ah, bh[j], acc[mf][j], 0, 0, 0);
                acc[mf][j] = __builtin_amdgcn_mfma_f32_16x16x32_bf16(ah, bl[j], acc[mf][j], 0, 0, 0);
                acc[mf][j] = __builtin_amdgcn_mfma_f32_16x16x32_bf16(al, bh[j], acc[mf][j], 0, 0, 0);
            }
        }
        __syncthreads();
    }

    // ---- epilogue: relu + b1, dot W2, reduce ----
    // C/D layout (HW-verified): col = lane&15, row = (lane>>4)*4 + reg.
#pragma unroll
    for (int mf = 0; mf < 4; ++mf) {
#pragma unroll
        for (int r = 0; r < 4; ++r) {
            float s = 0.0f;
#pragma unroll
            for (int j = 0; j < 2; ++j) {
                float h = acc[mf][j][r] + b1v[j];
                h = h > 0.0f ? h : 0.0f;
                s += h * w2v[j];
            }
            // sum across the 16 lanes (cols) sharing this row
            s += __shfl_xor(s, 1);
            s += __shfl_xor(s, 2);
            s += __shfl_xor(s, 4);
            s += __shfl_xor(s, 8);
            if (l15 == 0) partial[mf * 16 + g * 4 + r][wid] = s;
        }
    }
    __syncthreads();

    if (tid < 64) {
        const float s = partial[tid][0] + partial[tid][1] +
                        partial[tid][2] + partial[tid][3] + b2[0];
        scores[m0 + tid] = nz[tid] ? s : NEG_BIG;
    }
}

// ---------------------------------------------------------------------------
// Pass 2: per batch row, sel[t] = 1 iff frame t in top-k (stable rank-by-count,
// exactly matching lax.top_k's lower-index-first tie handling).
// ---------------------------------------------------------------------------
__global__ __launch_bounds__(256) void topk_kernel(
    const float* __restrict__ scores,  // [B*T]
    const int* __restrict__ kp,        // [1]
    int* __restrict__ sel)             // [B*T]
{
    __shared__ float srow[T];

    const int b     = blockIdx.x >> 3;   // 8 chunks of 256 frames per row
    const int chunk = blockIdx.x & 7;
    const float* row = scores + (size_t)b * T;

    for (int i = threadIdx.x; i < T / 4; i += 256)
        reinterpret_cast<float4*>(srow)[i] =
            reinterpret_cast<const float4*>(row)[i];
    __syncthreads();

    const int t   = chunk * 256 + threadIdx.x;
    const float s = srow[t];
    int cnt = 0;
    for (int i = 0; i < T / 4; ++i) {
        const float4 v = reinterpret_cast<const float4*>(srow)[i];
        const int base = i * 4;
        cnt += (v.x > s) || (v.x == s && (base + 0) < t);
        cnt += (v.y > s) || (v.y == s && (base + 1) < t);
        cnt += (v.z > s) || (v.z == s && (base + 2) < t);
        cnt += (v.w > s) || (v.w == s && (base + 3) < t);
    }
    const int k = kp[0];
    sel[(size_t)b * T + t] = (cnt < k) ? 1 : 0;
}

// ---------------------------------------------------------------------------
// Pass 3: out[m,:] = sel[m] ? x[m,:] : 0.
// ---------------------------------------------------------------------------
__global__ __launch_bounds__(256) void out_kernel(
    const float* __restrict__ x,
    const int* __restrict__ sel,
    float* __restrict__ out)
{
    const size_t total  = (size_t)B * T * (F / 4);   // float4 count
    const size_t stride = (size_t)gridDim.x * blockDim.x;
    for (size_t idx = (size_t)blockIdx.x * blockDim.x + threadIdx.x;
         idx < total; idx += stride) {
        const size_t frame = idx >> 7;               // F/4 = 128 float4 per frame
        float4 v = make_float4(0.0f, 0.0f, 0.0f, 0.0f);
        if (sel[frame])
            v = reinterpret_cast<const float4*>(x)[idx];
        reinterpret_cast<float4*>(out)[idx] = v;
    }
}

// ---------------------------------------------------------------------------
extern "C" void kernel_launch(void* const* d_in, const int* in_sizes, int n_in,
                              void* d_out, int out_size, void* d_ws, size_t ws_size,
                              hipStream_t stream)
{
    const float* x  = (const float*)d_in[0];
    const float* W1 = (const float*)d_in[1];
    const float* b1 = (const float*)d_in[2];
    const float* W2 = (const float*)d_in[3];
    const float* b2 = (const float*)d_in[4];
    const int*   kp = (const int*)d_in[5];

    char* ws = (char*)d_ws;
    unsigned short* WThi = (unsigned short*)ws;               // 131072 B
    unsigned short* WTlo = (unsigned short*)(ws + 131072);    // 131072 B
    float* scores        = (float*)(ws + 262144);             // 262144 B
    int*   sel           = (int*)(ws + 524288);               // 262144 B

    float* out = (float*)d_out;

    prep_w<<<256, 256, 0, stream>>>(W1, WThi, WTlo);
    score_kernel<<<(B * T) / 64, 256, 0, stream>>>(x, WThi, WTlo, b1, W2, b2, scores);
    topk_kernel<<<B * 8, 256, 0, stream>>>(scores, kp, sel);
    out_kernel<<<4096, 256, 0, stream>>>(x, sel, out);
}